// Round 10
// baseline (1300.880 us; speedup 1.0000x reference)
//
#include <hip/hip_runtime.h>
#include <math.h>
#include <float.h>

#define T_ 384
#define D_ 512
#define H_ 8
#define HD_ 64
#define K_ 48
#define LN_EPS 1e-5f
#define NTOK 768
#define NB 768
#define PSTRIDE (NTOK * D_)       // 393216 floats
#define PSTRIDE2 (PSTRIDE / 2)    // float2 units
#define T2 (T_ * T_)

// barrier state in device globals: zero-init at module load, NOT in poisoned ws.
// generation counter is monotonic across launches (same work every call).
__device__ unsigned g_cnt = 0;
__device__ unsigned g_gen = 0;

union SMem {
    struct { float A[32][33]; float B[32][65]; } ge;   // 12544 B (max)
    struct { float A[16][68]; float Bv[16][68]; } sc;  // 8704 B
    struct { float x[D_]; float logits[H_]; float hd[HD_]; } su;
    struct { float s[T_]; int sel[K_]; } tk;
    struct { float red[4][2]; } ln;
};

// sense-reversing grid barrier (device-scope atomics + fences; the same
// mechanism hip cooperative groups grid.sync() uses on CDNA).
__device__ __forceinline__ void gridbar() {
    __syncthreads();
    __threadfence();
    if (threadIdx.x == 0) {
        unsigned g = __hip_atomic_load(&g_gen, __ATOMIC_RELAXED, __HIP_MEMORY_SCOPE_AGENT);
        unsigned t = __hip_atomic_fetch_add(&g_cnt, 1u, __ATOMIC_ACQ_REL, __HIP_MEMORY_SCOPE_AGENT);
        if (t == NB - 1u) {
            __hip_atomic_store(&g_cnt, 0u, __ATOMIC_RELAXED, __HIP_MEMORY_SCOPE_AGENT);
            __hip_atomic_fetch_add(&g_gen, 1u, __ATOMIC_ACQ_REL, __HIP_MEMORY_SCOPE_AGENT);
        } else {
            while (__hip_atomic_load(&g_gen, __ATOMIC_ACQUIRE, __HIP_MEMORY_SCOPE_AGENT) == g)
                __builtin_amdgcn_s_sleep(2);
        }
    }
    __threadfence();
    __syncthreads();
}

// K-split tiled GEMM partials: 32r x 64c x 128K per block over 768 blocks.
__device__ __forceinline__ void gemm_part(SMem* sm, int bid, int tid,
                                          const float* __restrict__ in,
                                          const float* __restrict__ W,
                                          float* __restrict__ part) {
    int ks = bid / 192;
    int rem = bid - ks * 192;
    int c0 = (rem & 7) * 64, r0 = (rem >> 3) * 32;
    int kbase = ks * 128;
    float* pout = part + (size_t)ks * PSTRIDE;
    int ry = tid >> 4, cx = tid & 15;
    float acc[2][4];
#pragma unroll
    for (int r = 0; r < 2; ++r)
#pragma unroll
        for (int c = 0; c < 4; ++c) acc[r][c] = 0.f;
    int asr = tid >> 3, asc = (tid & 7) * 4;
    int bsr = tid >> 2, bsk = (tid & 3) * 8;
    for (int k0 = kbase; k0 < kbase + 128; k0 += 32) {
        float4 a4 = *(const float4*)&in[(size_t)(r0 + asr) * D_ + k0 + asc];
        sm->ge.A[asc + 0][asr] = a4.x;
        sm->ge.A[asc + 1][asr] = a4.y;
        sm->ge.A[asc + 2][asr] = a4.z;
        sm->ge.A[asc + 3][asr] = a4.w;
        float4 b4a = *(const float4*)&W[(size_t)(c0 + bsr) * D_ + k0 + bsk];
        float4 b4b = *(const float4*)&W[(size_t)(c0 + bsr) * D_ + k0 + bsk + 4];
        sm->ge.B[bsk + 0][bsr] = b4a.x;
        sm->ge.B[bsk + 1][bsr] = b4a.y;
        sm->ge.B[bsk + 2][bsr] = b4a.z;
        sm->ge.B[bsk + 3][bsr] = b4a.w;
        sm->ge.B[bsk + 4][bsr] = b4b.x;
        sm->ge.B[bsk + 5][bsr] = b4b.y;
        sm->ge.B[bsk + 6][bsr] = b4b.z;
        sm->ge.B[bsk + 7][bsr] = b4b.w;
        __syncthreads();
#pragma unroll
        for (int kk = 0; kk < 32; ++kk) {
            float2 a2 = *(const float2*)&sm->ge.A[kk][ry * 2];
            float4 b4 = *(const float4*)&sm->ge.B[kk][cx * 4];
            acc[0][0] += a2.x * b4.x; acc[0][1] += a2.x * b4.y;
            acc[0][2] += a2.x * b4.z; acc[0][3] += a2.x * b4.w;
            acc[1][0] += a2.y * b4.x; acc[1][1] += a2.y * b4.y;
            acc[1][2] += a2.y * b4.z; acc[1][3] += a2.y * b4.w;
        }
        __syncthreads();
    }
#pragma unroll
    for (int r = 0; r < 2; ++r) {
        float4 o;
        o.x = acc[r][0];
        o.y = acc[r][1];
        o.z = acc[r][2];
        o.w = acc[r][3];
        *(float4*)&pout[(size_t)(r0 + ry * 2 + r) * D_ + c0 + cx * 4] = o;
    }
}

__global__ __launch_bounds__(256, 3) void k_mega(
    const float* __restrict__ x, const float* __restrict__ g_w,
    const float* __restrict__ g_b, const float* __restrict__ sp_w,
    const float* __restrict__ sp_b, const float* __restrict__ gate_w,
    const float* __restrict__ gate_b, const float* __restrict__ U_w,
    const float* __restrict__ U_b, const float* __restrict__ ln_g,
    const float* __restrict__ ln_b, float* __restrict__ xs,
    float* __restrict__ gate, float* __restrict__ xo,
    float* __restrict__ part, float* __restrict__ spart,
    float* __restrict__ out) {
    __shared__ SMem sm;
    int bid = blockIdx.x, tid = threadIdx.x;

    // ---------------- phase 1: superposition (1 token / block) ----------------
    {
        const float* xt = x + (size_t)bid * D_;
        ((float2*)sm.su.x)[tid] = ((const float2*)xt)[tid];
        __syncthreads();
        int h = tid >> 5, l = tid & 31;
        float p = 0.f;
#pragma unroll
        for (int i = 0; i < 16; ++i) {
            int k = l + 32 * i;
            p += sm.su.x[k] * g_w[h * D_ + k];
        }
#pragma unroll
        for (int off = 16; off > 0; off >>= 1) p += __shfl_xor(p, off);
        if (l == 0) sm.su.logits[h] = p + g_b[h];
        __syncthreads();
        if (tid < HD_) {
            float m = sm.su.logits[0];
#pragma unroll
            for (int hh = 1; hh < H_; ++hh) m = fmaxf(m, sm.su.logits[hh]);
            float e[H_];
            float sum = 0.f;
#pragma unroll
            for (int hh = 0; hh < H_; ++hh) {
                e[hh] = expf(sm.su.logits[hh] - m);
                sum += e[hh];
            }
            float inv = 1.f / sum;
            float v = 0.f;
#pragma unroll
            for (int hh = 0; hh < H_; ++hh) v += e[hh] * inv * sm.su.x[hh * HD_ + tid];
            sm.su.hd[tid] = v;
        }
        __syncthreads();
        float a0 = sp_b[tid], a1 = sp_b[tid + 256];
        const float* w0 = sp_w + (size_t)tid * HD_;
        const float* w1 = sp_w + (size_t)(tid + 256) * HD_;
#pragma unroll
        for (int k = 0; k < HD_; k += 4) {
            float4 h4 = *(const float4*)&sm.su.hd[k];
            float4 u0 = *(const float4*)&w0[k];
            float4 u1 = *(const float4*)&w1[k];
            a0 += h4.x * u0.x + h4.y * u0.y + h4.z * u0.z + h4.w * u0.w;
            a1 += h4.x * u1.x + h4.y * u1.y + h4.z * u1.z + h4.w * u1.w;
        }
        xs[(size_t)bid * D_ + tid] = a0;
        xs[(size_t)bid * D_ + 256 + tid] = a1;
    }
    gridbar();
    // ---------------- phase 2: gate GEMM partials ----------------
    gemm_part(&sm, bid, tid, xs, gate_w, part);
    gridbar();
    // ---------------- phase 3: reduce 4 partials + bias + sigmoid ----------------
    {
        int idx = bid * 256 + tid;   // float2 index over [0, PSTRIDE2)
        const float2* p2 = (const float2*)part;
        float2 s = {0.f, 0.f};
#pragma unroll
        for (int q = 0; q < 4; ++q) {
            float2 a = p2[idx + q * PSTRIDE2];
            s.x += a.x;
            s.y += a.y;
        }
        float2 bb = ((const float2*)gate_b)[idx & 255];
        s.x = 1.f / (1.f + expf(-(s.x + bb.x)));
        s.y = 1.f / (1.f + expf(-(s.y + bb.y)));
        ((float2*)gate)[idx] = s;
    }
    gridbar();
    // ---------------- phase 4: scores Gram partials (576 active blocks) ----------------
    if (bid < 576) {
        int z = bid / 36;
        int rem = bid - z * 36;
        int i0 = (rem / 6) * 64, j0 = (rem % 6) * 64;
        int b = z >> 3, ks = z & 7;
        int kbase = ks * 64;
        int tx = tid & 15, ty = tid >> 4;
        float acc[4][4];
#pragma unroll
        for (int r = 0; r < 4; ++r)
#pragma unroll
            for (int c = 0; c < 4; ++c) acc[r][c] = 0.f;
        const float* gb = gate + (size_t)b * T_ * D_;
        int sr = tid >> 2, sc4 = (tid & 3) * 4;
        for (int k0 = kbase; k0 < kbase + 64; k0 += 16) {
            float4 av = *(const float4*)&gb[(size_t)(i0 + sr) * D_ + k0 + sc4];
            float4 bvv = *(const float4*)&gb[(size_t)(j0 + sr) * D_ + k0 + sc4];
            sm.sc.A[sc4 + 0][sr] = av.x * av.x;
            sm.sc.A[sc4 + 1][sr] = av.y * av.y;
            sm.sc.A[sc4 + 2][sr] = av.z * av.z;
            sm.sc.A[sc4 + 3][sr] = av.w * av.w;
            sm.sc.Bv[sc4 + 0][sr] = bvv.x * bvv.x;
            sm.sc.Bv[sc4 + 1][sr] = bvv.y * bvv.y;
            sm.sc.Bv[sc4 + 2][sr] = bvv.z * bvv.z;
            sm.sc.Bv[sc4 + 3][sr] = bvv.w * bvv.w;
            __syncthreads();
#pragma unroll
            for (int kk = 0; kk < 16; ++kk) {
                float4 a4 = *(const float4*)&sm.sc.A[kk][4 * ty];
                float4 b4 = *(const float4*)&sm.sc.Bv[kk][4 * tx];
                float ar[4] = {a4.x, a4.y, a4.z, a4.w};
                float bc[4] = {b4.x, b4.y, b4.z, b4.w};
#pragma unroll
                for (int r = 0; r < 4; ++r)
#pragma unroll
                    for (int c = 0; c < 4; ++c) acc[r][c] += ar[r] * bc[c];
            }
            __syncthreads();
        }
        float* sp = spart + (size_t)z * T2;
#pragma unroll
        for (int r = 0; r < 4; ++r) {
            float4 o;
            o.x = acc[r][0];
            o.y = acc[r][1];
            o.z = acc[r][2];
            o.w = acc[r][3];
            *(float4*)&sp[(size_t)(i0 + 4 * ty + r) * T_ + j0 + 4 * tx] = o;
        }
    }
    gridbar();
    // ---------------- phase 5: rank-based top-K + entangle (1 row / block) ----------------
    {
        int b = bid / T_;
        int i = bid - b * T_;
        // stage summed score row (no sqrt: monotonic, same top-K set)
        for (int j = tid; j < T_; j += 256) {
            float s = 0.f;
#pragma unroll
            for (int ks = 0; ks < 8; ++ks)
                s += spart[(size_t)(b * 8 + ks) * T2 + (size_t)i * T_ + j];
            sm.tk.s[j] = s;
        }
        __syncthreads();
        // exact rank (JAX tie semantics: value desc, index asc)
        for (int j = tid; j < T_; j += 256) {
            float v = sm.tk.s[j];
            int c = 0;
            for (int j2 = 0; j2 < T_; ++j2) {
                float u = sm.tk.s[j2];
                c += (u > v) || (u == v && j2 < j);
            }
            if (c < K_) sm.tk.sel[c] = j;
        }
        __syncthreads();
        const float2* g2 = (const float2*)gate;
        float2 s = {0.f, 0.f};
        int rb = b * T_;
        for (int n = 0; n < K_; ++n) {
            int j = sm.tk.sel[n];
            float2 g = g2[(size_t)(rb + j) * 256 + tid];
            s.x += g.x;
            s.y += g.y;
        }
        float2 gi = g2[(size_t)bid * 256 + tid];
        float2 xv = ((const float2*)xs)[(size_t)bid * 256 + tid];
        float2 o;
        o.x = xv.x + gi.x * s.x;
        o.y = xv.y + gi.y * s.y;
        ((float2*)xo)[(size_t)bid * 256 + tid] = o;
    }
    gridbar();
    // ---------------- phase 6: U GEMM partials ----------------
    gemm_part(&sm, bid, tid, xo, U_w, part);
    gridbar();
    // ---------------- phase 7: reduce + bias + LayerNorm (1 row / block) ----------------
    {
        int base = bid * 256 + tid;  // float2 index; one 256-float2 row per block
        const float2* p2 = (const float2*)part;
        float2 s = {0.f, 0.f};
#pragma unroll
        for (int q = 0; q < 4; ++q) {
            float2 a = p2[base + q * PSTRIDE2];
            s.x += a.x;
            s.y += a.y;
        }
        float2 ub = ((const float2*)U_b)[tid];
        s.x += ub.x;
        s.y += ub.y;
        float sum = s.x + s.y;
        float sq = s.x * s.x + s.y * s.y;
#pragma unroll
        for (int off = 32; off > 0; off >>= 1) {
            sum += __shfl_xor(sum, off);
            sq += __shfl_xor(sq, off);
        }
        int wave = tid >> 6;
        if ((tid & 63) == 0) {
            sm.ln.red[wave][0] = sum;
            sm.ln.red[wave][1] = sq;
        }
        __syncthreads();
        float m1 = sm.ln.red[0][0] + sm.ln.red[1][0] + sm.ln.red[2][0] + sm.ln.red[3][0];
        float m2 = sm.ln.red[0][1] + sm.ln.red[1][1] + sm.ln.red[2][1] + sm.ln.red[3][1];
        float mu = m1 * (1.f / D_);
        float var = fmaxf(m2 * (1.f / D_) - mu * mu, 0.f);
        float inv = rsqrtf(var + LN_EPS);
        float2 lg = ((const float2*)ln_g)[tid];
        float2 lb = ((const float2*)ln_b)[tid];
        float2 o;
        o.x = lg.x * (s.x - mu) * inv + lb.x;
        o.y = lg.y * (s.y - mu) * inv + lb.y;
        ((float2*)out)[base] = o;
    }
}

// --------------------------------------------------------------------- launch
extern "C" void kernel_launch(void* const* d_in, const int* in_sizes, int n_in,
                              void* d_out, int out_size, void* d_ws, size_t ws_size,
                              hipStream_t stream) {
    const float* x      = (const float*)d_in[0];
    const float* g_w    = (const float*)d_in[1];
    const float* g_b    = (const float*)d_in[2];
    const float* sp_w   = (const float*)d_in[3];
    const float* sp_b   = (const float*)d_in[4];
    const float* gate_w = (const float*)d_in[5];
    const float* gate_b = (const float*)d_in[6];
    const float* U_w    = (const float*)d_in[7];
    const float* U_b    = (const float*)d_in[8];
    const float* ln_g   = (const float*)d_in[9];
    const float* ln_b   = (const float*)d_in[10];

    float* ws    = (float*)d_ws;
    float* xs    = ws;                   // 393216
    float* gate  = xs + PSTRIDE;         // 393216
    float* xo    = gate + PSTRIDE;       // 393216
    float* part  = xo + PSTRIDE;         // 4 * 393216
    float* spart = part + 4 * PSTRIDE;   // 16 * 147456

    k_mega<<<NB, 256, 0, stream>>>(x, g_w, g_b, sp_w, sp_b, gate_w, gate_b,
                                   U_w, U_b, ln_g, ln_b, xs, gate, xo, part,
                                   spart, (float*)d_out);
}

// Round 12
// 166.621 us; speedup vs baseline: 7.8074x; 7.8074x over previous
//
#include <hip/hip_runtime.h>
#include <math.h>
#include <float.h>

#define T_ 384
#define D_ 512
#define H_ 8
#define HD_ 64
#define K_ 48
#define LN_EPS 1e-5f
#define NTOK 768
#define PSTRIDE (NTOK * D_)       // 393216 floats
#define T2 (T_ * T_)

// ---------- k1: superposition per token (blocks 0..767) + M/Mb precompute
// (blocks 768..895). M = gate_w @ sp_w stored TRANSPOSED: MT[j][d] (64 x 512);
// Mb = gate_b + gate_w @ sp_b.
__global__ __launch_bounds__(256) void k_super_m(
    const float* __restrict__ x, const float* __restrict__ g_w,
    const float* __restrict__ g_b, const float* __restrict__ sp_w,
    const float* __restrict__ sp_b, const float* __restrict__ gate_w,
    const float* __restrict__ gate_b, float* __restrict__ xs,
    float* __restrict__ hd_g, float* __restrict__ MT, float* __restrict__ Mb) {
    __shared__ float xsh[D_];
    __shared__ float logits[H_];
    __shared__ float hdv[HD_];
    int bid = blockIdx.x, tid = threadIdx.x;
    if (bid < NTOK) {
        const float* xt = x + (size_t)bid * D_;
        ((float2*)xsh)[tid] = ((const float2*)xt)[tid];
        __syncthreads();
        int h = tid >> 5, l = tid & 31;
        float p = 0.f;
#pragma unroll
        for (int i = 0; i < 16; ++i) {
            int k = l + 32 * i;
            p += xsh[k] * g_w[h * D_ + k];
        }
#pragma unroll
        for (int off = 16; off > 0; off >>= 1) p += __shfl_xor(p, off);
        if (l == 0) logits[h] = p + g_b[h];
        __syncthreads();
        if (tid < HD_) {
            float m = logits[0];
#pragma unroll
            for (int hh = 1; hh < H_; ++hh) m = fmaxf(m, logits[hh]);
            float e[H_];
            float sum = 0.f;
#pragma unroll
            for (int hh = 0; hh < H_; ++hh) { e[hh] = expf(logits[hh] - m); sum += e[hh]; }
            float inv = 1.f / sum;
            float v = 0.f;
#pragma unroll
            for (int hh = 0; hh < H_; ++hh) v += e[hh] * inv * xsh[hh * HD_ + tid];
            hdv[tid] = v;
            hd_g[(size_t)bid * HD_ + tid] = v;
        }
        __syncthreads();
        float a0 = sp_b[tid], a1 = sp_b[tid + 256];
        const float* w0 = sp_w + (size_t)tid * HD_;
        const float* w1 = sp_w + (size_t)(tid + 256) * HD_;
#pragma unroll
        for (int k = 0; k < HD_; k += 4) {
            float4 h4 = *(const float4*)&hdv[k];
            float4 u0 = *(const float4*)&w0[k];
            float4 u1 = *(const float4*)&w1[k];
            a0 += h4.x * u0.x + h4.y * u0.y + h4.z * u0.z + h4.w * u0.w;
            a1 += h4.x * u1.x + h4.y * u1.y + h4.z * u1.z + h4.w * u1.w;
        }
        xs[(size_t)bid * D_ + tid] = a0;
        xs[(size_t)bid * D_ + 256 + tid] = a1;
    } else {
        // M/Mb block: 4 d-rows per block, thread = (r = tid>>6, l = tid&63)
        int d = (bid - NTOK) * 4 + (tid >> 6);
        int l = tid & 63;
        const float* gw = gate_w + (size_t)d * D_;
        // Mb[d] = gate_b[d] + sum_k gate_w[d,k] * sp_b[k]
        float p = 0.f;
#pragma unroll
        for (int i = 0; i < 8; ++i) p += gw[l + 64 * i] * sp_b[l + 64 * i];
#pragma unroll
        for (int off = 32; off > 0; off >>= 1) p += __shfl_xor(p, off);
        if (l == 0) Mb[d] = p + gate_b[d];
        // MT[l][d] = sum_k gate_w[d,k] * sp_w[k,l]
        float acc = 0.f;
        for (int k = 0; k < D_; k += 4) {
            float4 a4 = *(const float4*)&gw[k];
            acc += a4.x * sp_w[(k + 0) * HD_ + l] + a4.y * sp_w[(k + 1) * HD_ + l] +
                   a4.z * sp_w[(k + 2) * HD_ + l] + a4.w * sp_w[(k + 3) * HD_ + l];
        }
        MT[(size_t)l * D_ + d] = acc;
    }
}

// ---------- k2: gate = sigmoid(hd @ M^T + Mb) ; K = 64, no LDS
// grid 768 = (96 token-tiles of 8) x (8 col-tiles of 64); thread: 2 tokens x 1 col
__global__ __launch_bounds__(256) void k_gate(const float* __restrict__ hd_g,
                                              const float* __restrict__ MT,
                                              const float* __restrict__ Mb,
                                              float* __restrict__ gate) {
    int bid = blockIdx.x, tid = threadIdx.x;
    int t0 = (bid >> 3) * 8, c0 = (bid & 7) * 64;
    int rr = tid >> 6, c = tid & 63;
    int ta = t0 + rr, tb = t0 + rr + 4;
    const float4* hd4 = (const float4*)hd_g;
    float acc0 = 0.f, acc1 = 0.f;
#pragma unroll
    for (int j4 = 0; j4 < 16; ++j4) {
        float4 h0 = hd4[ta * 16 + j4];
        float4 h1 = hd4[tb * 16 + j4];
        int j = j4 * 4;
        float m0 = MT[(size_t)(j + 0) * D_ + c0 + c];
        float m1 = MT[(size_t)(j + 1) * D_ + c0 + c];
        float m2 = MT[(size_t)(j + 2) * D_ + c0 + c];
        float m3 = MT[(size_t)(j + 3) * D_ + c0 + c];
        acc0 += h0.x * m0 + h0.y * m1 + h0.z * m2 + h0.w * m3;
        acc1 += h1.x * m0 + h1.y * m1 + h1.z * m2 + h1.w * m3;
    }
    float mb = Mb[c0 + c];
    gate[(size_t)ta * D_ + c0 + c] = 1.f / (1.f + expf(-(acc0 + mb)));
    gate[(size_t)tb * D_ + c0 + c] = 1.f / (1.f + expf(-(acc1 + mb)));
}

// ---------- k3: scores Gram partials (no sqrt): 64x64 x 64K tiles, z = b*8+ks
__global__ __launch_bounds__(256) void k_scores_part(const float* __restrict__ gate,
                                                     float* __restrict__ spart) {
    int z = blockIdx.z;
    int b = z >> 3, ks = z & 7;
    int kbase = ks * 64;
    int i0 = blockIdx.y * 64, j0 = blockIdx.x * 64;
    int tid = threadIdx.x;
    int tx = tid & 15, ty = tid >> 4;
    __shared__ float Ash[16][68];
    __shared__ float Bsh[16][68];
    float acc[4][4];
#pragma unroll
    for (int r = 0; r < 4; ++r)
#pragma unroll
        for (int c = 0; c < 4; ++c) acc[r][c] = 0.f;
    const float* gb = gate + (size_t)b * T_ * D_;
    int sr = tid >> 2, sc4 = (tid & 3) * 4;
    for (int k0 = kbase; k0 < kbase + 64; k0 += 16) {
        float4 av = *(const float4*)&gb[(size_t)(i0 + sr) * D_ + k0 + sc4];
        float4 bvv = *(const float4*)&gb[(size_t)(j0 + sr) * D_ + k0 + sc4];
        Ash[sc4 + 0][sr] = av.x * av.x;
        Ash[sc4 + 1][sr] = av.y * av.y;
        Ash[sc4 + 2][sr] = av.z * av.z;
        Ash[sc4 + 3][sr] = av.w * av.w;
        Bsh[sc4 + 0][sr] = bvv.x * bvv.x;
        Bsh[sc4 + 1][sr] = bvv.y * bvv.y;
        Bsh[sc4 + 2][sr] = bvv.z * bvv.z;
        Bsh[sc4 + 3][sr] = bvv.w * bvv.w;
        __syncthreads();
#pragma unroll
        for (int kk = 0; kk < 16; ++kk) {
            float4 a4 = *(const float4*)&Ash[kk][4 * ty];
            float4 b4 = *(const float4*)&Bsh[kk][4 * tx];
            float ar[4] = {a4.x, a4.y, a4.z, a4.w};
            float bc[4] = {b4.x, b4.y, b4.z, b4.w};
#pragma unroll
            for (int r = 0; r < 4; ++r)
#pragma unroll
                for (int c = 0; c < 4; ++c) acc[r][c] += ar[r] * bc[c];
        }
        __syncthreads();
    }
    float* sp = spart + (size_t)z * T2;
#pragma unroll
    for (int r = 0; r < 4; ++r) {
        float4 o;
        o.x = acc[r][0];
        o.y = acc[r][1];
        o.z = acc[r][2];
        o.w = acc[r][3];
        *(float4*)&sp[(size_t)(i0 + 4 * ty + r) * T_ + j0 + 4 * tx] = o;
    }
}

// ---------- k4: rank-based top-K + entangle, 1 row / block, 256 threads
// rank_j = #{j2 : s[j2]>s[j] or (s[j2]==s[j] and j2<j)} matches JAX
// top_k order (value desc, index asc); sqrt dropped (monotonic).
__global__ __launch_bounds__(256) void k_topk_ent(const float* __restrict__ spart,
                                                  const float* __restrict__ gate,
                                                  const float* __restrict__ xs,
                                                  float* __restrict__ xo) {
    __shared__ float s[T_];
    __shared__ int sel[K_];
    int row = blockIdx.x, tid = threadIdx.x;
    int b = row / T_;
    int i = row - b * T_;
    for (int j = tid; j < T_; j += 256) {
        float acc = 0.f;
#pragma unroll
        for (int ks = 0; ks < 8; ++ks)
            acc += spart[(size_t)(b * 8 + ks) * T2 + (size_t)i * T_ + j];
        s[j] = acc;
    }
    __syncthreads();
    for (int j = tid; j < T_; j += 256) {
        float v = s[j];
        int cnt = 0;
        for (int j2 = 0; j2 < T_; ++j2) {
            float u = s[j2];
            cnt += (u > v) || (u == v && j2 < j);
        }
        if (cnt < K_) sel[cnt] = j;
    }
    __syncthreads();
    const float2* g2 = (const float2*)gate;
    float2 sum = {0.f, 0.f};
    int rb = b * T_;
    for (int n = 0; n < K_; ++n) {
        int j = sel[n];
        float2 g = g2[(size_t)(rb + j) * 256 + tid];
        sum.x += g.x;
        sum.y += g.y;
    }
    float2 gi = g2[(size_t)row * 256 + tid];
    float2 xv = ((const float2*)xs)[(size_t)row * 256 + tid];
    float2 o;
    o.x = xv.x + gi.x * sum.x;
    o.y = xv.y + gi.y * sum.y;
    ((float2*)xo)[(size_t)row * 256 + tid] = o;
}

// ---------- k5: U GEMM partials, 32r x 64c x 128K, grid (8, 24, 4)
__global__ __launch_bounds__(256) void k_wgemm_part(const float* __restrict__ in,
                                                    const float* __restrict__ W,
                                                    float* __restrict__ part) {
    int c0 = blockIdx.x * 64, r0 = blockIdx.y * 32;
    int kbase = blockIdx.z * 128;
    float* pout = part + (size_t)blockIdx.z * PSTRIDE;
    int tid = threadIdx.x;
    int ry = tid >> 4, cx = tid & 15;
    __shared__ float A_shT[32][33];
    __shared__ float B_sh[32][65];
    float acc[2][4];
#pragma unroll
    for (int r = 0; r < 2; ++r)
#pragma unroll
        for (int c = 0; c < 4; ++c) acc[r][c] = 0.f;
    int asr = tid >> 3, asc = (tid & 7) * 4;
    int bsr = tid >> 2, bsk = (tid & 3) * 8;
    for (int k0 = kbase; k0 < kbase + 128; k0 += 32) {
        float4 a4 = *(const float4*)&in[(size_t)(r0 + asr) * D_ + k0 + asc];
        A_shT[asc + 0][asr] = a4.x;
        A_shT[asc + 1][asr] = a4.y;
        A_shT[asc + 2][asr] = a4.z;
        A_shT[asc + 3][asr] = a4.w;
        float4 b4a = *(const float4*)&W[(size_t)(c0 + bsr) * D_ + k0 + bsk];
        float4 b4b = *(const float4*)&W[(size_t)(c0 + bsr) * D_ + k0 + bsk + 4];
        B_sh[bsk + 0][bsr] = b4a.x;
        B_sh[bsk + 1][bsr] = b4a.y;
        B_sh[bsk + 2][bsr] = b4a.z;
        B_sh[bsk + 3][bsr] = b4a.w;
        B_sh[bsk + 4][bsr] = b4b.x;
        B_sh[bsk + 5][bsr] = b4b.y;
        B_sh[bsk + 6][bsr] = b4b.z;
        B_sh[bsk + 7][bsr] = b4b.w;
        __syncthreads();
#pragma unroll
        for (int kk = 0; kk < 32; ++kk) {
            float2 a2 = *(const float2*)&A_shT[kk][ry * 2];
            float4 b4 = *(const float4*)&B_sh[kk][cx * 4];
            acc[0][0] += a2.x * b4.x; acc[0][1] += a2.x * b4.y;
            acc[0][2] += a2.x * b4.z; acc[0][3] += a2.x * b4.w;
            acc[1][0] += a2.y * b4.x; acc[1][1] += a2.y * b4.y;
            acc[1][2] += a2.y * b4.z; acc[1][3] += a2.y * b4.w;
        }
        __syncthreads();
    }
#pragma unroll
    for (int r = 0; r < 2; ++r) {
        float4 o;
        o.x = acc[r][0];
        o.y = acc[r][1];
        o.z = acc[r][2];
        o.w = acc[r][3];
        *(float4*)&pout[(size_t)(r0 + ry * 2 + r) * D_ + c0 + cx * 4] = o;
    }
}

// ---------- k6: reduce 4 U-partials + bias + LayerNorm (2 rows / block)
__global__ __launch_bounds__(256) void k_wred_ln(const float* __restrict__ part,
                                                 const float* __restrict__ U_b,
                                                 const float* __restrict__ ln_g,
                                                 const float* __restrict__ ln_b,
                                                 float* __restrict__ out) {
    int tid = threadIdx.x;
    int idx = blockIdx.x * 256 + tid;   // float4 idx; 128 float4/row; 2 rows/block
    const float4* p = (const float4*)part;
    float4 s = {0.f, 0.f, 0.f, 0.f};
#pragma unroll
    for (int q = 0; q < 4; ++q) {
        float4 a = p[idx + q * (PSTRIDE / 4)];
        s.x += a.x; s.y += a.y; s.z += a.z; s.w += a.w;
    }
    float4 ub = ((const float4*)U_b)[tid & 127];
    s.x += ub.x; s.y += ub.y; s.z += ub.z; s.w += ub.w;
    float sum = s.x + s.y + s.z + s.w;
    float sq = s.x * s.x + s.y * s.y + s.z * s.z + s.w * s.w;
#pragma unroll
    for (int off = 32; off > 0; off >>= 1) {
        sum += __shfl_xor(sum, off);
        sq += __shfl_xor(sq, off);
    }
    __shared__ float red[4][2];
    int wave = tid >> 6;
    if ((tid & 63) == 0) { red[wave][0] = sum; red[wave][1] = sq; }
    __syncthreads();
    int rw = (tid >> 7) * 2;
    float m1 = red[rw][0] + red[rw + 1][0];
    float m2 = red[rw][1] + red[rw + 1][1];
    float mu = m1 * (1.f / D_);
    float var = fmaxf(m2 * (1.f / D_) - mu * mu, 0.f);
    float inv = rsqrtf(var + LN_EPS);
    float4 lg = ((const float4*)ln_g)[tid & 127];
    float4 lb = ((const float4*)ln_b)[tid & 127];
    float4 o;
    o.x = lg.x * (s.x - mu) * inv + lb.x;
    o.y = lg.y * (s.y - mu) * inv + lb.y;
    o.z = lg.z * (s.z - mu) * inv + lb.z;
    o.w = lg.w * (s.w - mu) * inv + lb.w;
    ((float4*)out)[idx] = o;
}

// --------------------------------------------------------------------- launch
extern "C" void kernel_launch(void* const* d_in, const int* in_sizes, int n_in,
                              void* d_out, int out_size, void* d_ws, size_t ws_size,
                              hipStream_t stream) {
    const float* x      = (const float*)d_in[0];
    const float* g_w    = (const float*)d_in[1];
    const float* g_b    = (const float*)d_in[2];
    const float* sp_w   = (const float*)d_in[3];
    const float* sp_b   = (const float*)d_in[4];
    const float* gate_w = (const float*)d_in[5];
    const float* gate_b = (const float*)d_in[6];
    const float* U_w    = (const float*)d_in[7];
    const float* U_b    = (const float*)d_in[8];
    const float* ln_g   = (const float*)d_in[9];
    const float* ln_b   = (const float*)d_in[10];

    float* ws    = (float*)d_ws;
    float* xs    = ws;                   // 393216
    float* gate  = xs + PSTRIDE;         // 393216
    float* xo    = gate + PSTRIDE;       // 393216
    float* hd_g  = xo + PSTRIDE;         // 49152
    float* MT    = hd_g + 49152;         // 32768
    float* Mb    = MT + 32768;           // 512
    float* part  = Mb + 512;             // 4 * 393216
    float* spart = part + 4 * PSTRIDE;   // 16 * 147456

    k_super_m<<<NTOK + 128, 256, 0, stream>>>(x, g_w, g_b, sp_w, sp_b, gate_w,
                                              gate_b, xs, hd_g, MT, Mb);
    k_gate<<<NTOK, 256, 0, stream>>>(hd_g, MT, Mb, gate);
    k_scores_part<<<dim3(T_ / 64, T_ / 64, 16), 256, 0, stream>>>(gate, spart);
    k_topk_ent<<<NTOK, 256, 0, stream>>>(spart, gate, xs, xo);
    k_wgemm_part<<<dim3(D_ / 64, NTOK / 32, 4), 256, 0, stream>>>(xo, U_w, part);
    k_wred_ln<<<NTOK * D_ / 1024, 256, 0, stream>>>(part, U_b, ln_g, ln_b, (float*)d_out);
}